// Round 7
// baseline (1471.086 us; speedup 1.0000x reference)
//
#include <hip/hip_runtime.h>
#include <math.h>

#define NU 60001
#define NI 40001
#define NN 100002   // NU + NI
#define EG 1000000
#define EB 500000
#define BATCH 4096

typedef float floatx2 __attribute__((ext_vector_type(2)));
typedef short bf16x8 __attribute__((ext_vector_type(8)));
typedef float f32x4 __attribute__((ext_vector_type(4)));

// ---------- helpers ----------
__device__ inline float wave_sum(float v) {
#pragma unroll
  for (int off = 32; off > 0; off >>= 1) v += __shfl_down(v, off);
  return __shfl(v, 0);
}

__device__ inline float sub_sum16(float v) {  // reduce within 16-lane subgroup
#pragma unroll
  for (int off = 8; off > 0; off >>= 1) v += __shfl_xor(v, off);
  return v;
}

__device__ inline float dot4(float4 a, float4 b) {
  return fmaf(a.x, b.x, fmaf(a.y, b.y, fmaf(a.z, b.z, a.w * b.w)));
}

__device__ inline unsigned short f2b(float f) {  // fp32 -> bf16 RNE
  unsigned u = __float_as_uint(f);
  return (unsigned short)((u + 0x7fffu + ((u >> 16) & 1u)) >> 16);
}
__device__ inline float b2f(unsigned short h) {
  return __uint_as_float((unsigned)h << 16);
}
__device__ inline float4 ld4b(const unsigned short* p) {
  ushort4 u = *(const ushort4*)p;
  return make_float4(b2f(u.x), b2f(u.y), b2f(u.z), b2f(u.w));
}

// fp8 e4m3 (OCP) hardware converts
__device__ inline unsigned char f2fp8(float f) {
  return (unsigned char)(__builtin_amdgcn_cvt_pk_fp8_f32(f, f, 0, false) & 0xff);
}
__device__ inline unsigned int pack4_fp8(float4 v) {
  int pk = __builtin_amdgcn_cvt_pk_fp8_f32(v.x, v.y, 0, false);
  pk = __builtin_amdgcn_cvt_pk_fp8_f32(v.z, v.w, pk, true);
  return (unsigned int)pk;
}

// ---------- fp8 concat table ----------
__global__ void k_tofp8_concat(const float4* __restrict__ ue, const float4* __restrict__ ie,
                               unsigned int* __restrict__ out) {
  long i = (long)blockIdx.x * blockDim.x + threadIdx.x;  // over NN*16 float4s
  if (i >= (long)NN * 16) return;
  float4 v = (i < (long)NU * 16) ? ue[i] : ie[i - (long)NU * 16];
  out[i] = pack4_fp8(v);
}

// ---------- CSR build, batched over 4 sets (0=global, 1..3=behavior) ----------
__global__ void k_deg(const int* __restrict__ eg, const int* __restrict__ eb,
                      int* __restrict__ cnt4) {
  int set = blockIdx.y;
  int E = set ? EB : EG;
  int e = blockIdx.x * blockDim.x + threadIdx.x;
  if (e >= E) return;
  const int* dst = set ? (eb + (long)(set - 1) * 2 * EB + EB) : (eg + EG);
  atomicAdd(cnt4 + set * NN + dst[e], 1);
}

__global__ void k_scanA(const int* __restrict__ cnt, int* __restrict__ offs,
                        int* __restrict__ part) {
  __shared__ int sd[256];
  int t = threadIdx.x, set = blockIdx.y;
  int base = set * NN;
  int i0 = blockIdx.x * 512 + 2 * t, i1 = i0 + 1;
  int a = (i0 < NN) ? cnt[base + i0] : 0;
  int b = (i1 < NN) ? cnt[base + i1] : 0;
  sd[t] = a + b;
  __syncthreads();
  for (int off = 1; off < 256; off <<= 1) {
    int v = (t >= off) ? sd[t - off] : 0;
    __syncthreads();
    sd[t] += v;
    __syncthreads();
  }
  int excl = (t > 0) ? sd[t - 1] : 0;
  if (i0 < NN) offs[base + i0] = excl;
  if (i1 < NN) offs[base + i1] = excl + a;
  if (t == 255) part[set * 256 + blockIdx.x] = sd[255];
}

__global__ void k_scanB(int* __restrict__ part) {
  __shared__ int sd[256];
  int t = threadIdx.x, set = blockIdx.x;
  sd[t] = (t < 196) ? part[set * 256 + t] : 0;
  __syncthreads();
  for (int off = 1; off < 256; off <<= 1) {
    int v = (t >= off) ? sd[t - off] : 0;
    __syncthreads();
    sd[t] += v;
    __syncthreads();
  }
  part[set * 256 + t] = (t > 0) ? sd[t - 1] : 0;
}

__global__ void k_scanC(int* __restrict__ offs, const int* __restrict__ part,
                        int* __restrict__ curs, const int* __restrict__ cnt,
                        float* __restrict__ dinv) {
  int i = blockIdx.x * blockDim.x + threadIdx.x;
  int set = blockIdx.y;
  if (i < NN) {
    int gi = set * NN + i;
    int v = offs[gi] + part[set * 256 + (i >> 9)];
    offs[gi] = v;
    curs[gi] = v;
    int c = cnt[gi];
    dinv[gi] = (c > 0) ? rsqrtf((float)c) : 0.f;
  }
}

// edge payload: x = src byte-offset into fp8 table (src*64), y = coef bits
__global__ void k_bucket(const int* __restrict__ eg, const int* __restrict__ eb,
                         const float* __restrict__ dinv, int* __restrict__ curs,
                         int2* __restrict__ edges) {
  int set = blockIdx.y;
  int E = set ? EB : EG;
  int e = blockIdx.x * blockDim.x + threadIdx.x;
  if (e >= E) return;
  const int* sp = set ? (eb + (long)(set - 1) * 2 * EB) : eg;
  int s = sp[e], d = sp[E + e];
  int pos = atomicAdd(curs + set * NN + d, 1);
  long ebase = set ? (EG + (long)(set - 1) * EB) : 0;
  edges[ebase + pos] =
      make_int2(s << 6, __float_as_int(dinv[set * NN + s] * dinv[set * NN + d]));
}

// ---------- degree-sorted node permutation (counting sort, 64 bins) ----------
__global__ void k_hist(const int* __restrict__ cnt4, int* __restrict__ hist) {
  __shared__ int lh[64];
  int t = threadIdx.x;
  if (t < 64) lh[t] = 0;
  __syncthreads();
  int i = blockIdx.x * 256 + t, set = blockIdx.y;
  if (i < NN) atomicAdd(&lh[min(cnt4[set * NN + i], 63)], 1);
  __syncthreads();
  if (t < 64 && lh[t]) atomicAdd(&hist[set * 64 + t], lh[t]);
}

__global__ void k_scan64(int* __restrict__ hist, int* __restrict__ bcur) {
  int t = threadIdx.x;
  if (t < 4) {
    int s = 0;
    for (int b = 0; b < 64; b++) {
      int v = hist[t * 64 + b];
      hist[t * 64 + b] = s;
      bcur[t * 64 + b] = s;
      s += v;
    }
  }
}

__global__ void k_perm(const int* __restrict__ cnt4, int* __restrict__ bcur,
                       int* __restrict__ perm) {
  int i = blockIdx.x * 256 + threadIdx.x, set = blockIdx.y;
  if (i < NN) {
    int d = min(cnt4[set * NN + i], 63);
    int p = atomicAdd(&bcur[set * 64 + d], 1);
    perm[set * NN + p] = i;
  }
}

// ---------- fused GCN layer: gather -> MFMA matvec -> bias -> l2norm -> out ----------
// 16 nodes per block, processed in degree-sorted order (perm).
// MODE 0: global l1  (tb=TB8,  out8=AGG8)
// MODE 1: global l2  (tb=AGG8, base=ue/ie f32, res16=G16, out8=TB8 shadow)
// MODE 2: behavior l1 (tb=TB8, out8=AGG8+set*NE), set = blockIdx.y
// MODE 3: behavior l2 (tb=AGG8+set*NE, base16=G16, res16=B16+set*NE)
template <int MODE>
__global__ void __launch_bounds__(256) k_gcn(
    const unsigned char* __restrict__ tb, const int2* __restrict__ edges,
    const int* __restrict__ offs, const int* __restrict__ cnt,
    const int* __restrict__ perm, const float* __restrict__ Wb,
    const float* __restrict__ biasb, const float* __restrict__ basef,
    const float* __restrict__ base2f, const unsigned short* __restrict__ base16,
    unsigned short* __restrict__ res16, unsigned char* __restrict__ out8) {
  __shared__ __align__(16) short accs[16][72];
  __shared__ float ssq[16][4];
  const long NE = (long)NN * 64;

  int t = threadIdx.x;
  int w = t >> 6, lane = t & 63;
  int sub = lane >> 4, sl = lane & 15;
  int set = blockIdx.y;

  const float *W, *bias;
  if (MODE <= 1) { W = Wb; bias = biasb; }
  else {
    W = Wb + (long)set * 8192 + (MODE == 3 ? 4096 : 0);
    bias = biasb + set * 128 + (MODE == 3 ? 64 : 0);
  }
  int cs = (MODE >= 2) ? (1 + set) : 0;
  const unsigned char* tbl = (MODE == 3) ? tb + (long)set * NE : tb;
  const int2* edg = (MODE >= 2) ? edges + EG + (long)set * EB : edges;
  const int* offp = offs + cs * NN;
  const int* cntp = cnt + cs * NN;
  const int* permp = perm + cs * NN;

  // ---- B-frags: W columns in registers, bf16 ----
  int ncol = (w << 4) + sl;
  bf16x8 bf0, bf1;
#pragma unroll
  for (int j = 0; j < 8; j++) {
    bf0[j] = (short)f2b(W[(sub * 8 + j) * 64 + ncol]);
    bf1[j] = (short)f2b(W[(32 + sub * 8 + j) * 64 + ncol]);
  }
  float bias_n = bias[ncol];

  // ---- gather: node per subgroup, degree-sorted rank order ----
  int nb0 = blockIdx.x * 16;
  int rank = nb0 + (w << 2) + sub;
  float4 acc = make_float4(0.f, 0.f, 0.f, 0.f);
  int st = 0, deg = 0;
  if (rank < NN) {
    int node = permp[rank];
    st = offp[node];
    deg = cntp[node];
  }
  int mx = deg;
  mx = max(mx, __shfl_xor(mx, 16));
  mx = max(mx, __shfl_xor(mx, 32));
  int lbase = lane & 48;  // sub*16
  for (int ch = 0; ch < mx; ch += 16) {
    int rem = deg - ch;
    int2 e = (sl < rem) ? edg[st + ch + sl] : make_int2(0, 0);
#pragma unroll
    for (int i = 0; i < 16; i += 4) {
      int j0 = lbase + i;
      int o0 = __shfl(e.x, j0),     c0i = __shfl(e.y, j0);
      int o1 = __shfl(e.x, j0 + 1), c1i = __shfl(e.y, j0 + 1);
      int o2 = __shfl(e.x, j0 + 2), c2i = __shfl(e.y, j0 + 2);
      int o3 = __shfl(e.x, j0 + 3), c3i = __shfl(e.y, j0 + 3);
      unsigned r0 = *(const unsigned*)(tbl + o0 + (sl << 2));
      unsigned r1 = *(const unsigned*)(tbl + o1 + (sl << 2));
      unsigned r2 = *(const unsigned*)(tbl + o2 + (sl << 2));
      unsigned r3 = *(const unsigned*)(tbl + o3 + (sl << 2));
      float c0 = __int_as_float(c0i), c1 = __int_as_float(c1i);
      float c2 = __int_as_float(c2i), c3 = __int_as_float(c3i);
      floatx2 l0 = __builtin_amdgcn_cvt_pk_f32_fp8(r0, false);
      floatx2 h0 = __builtin_amdgcn_cvt_pk_f32_fp8(r0, true);
      acc.x = fmaf(l0.x, c0, acc.x); acc.y = fmaf(l0.y, c0, acc.y);
      acc.z = fmaf(h0.x, c0, acc.z); acc.w = fmaf(h0.y, c0, acc.w);
      floatx2 l1 = __builtin_amdgcn_cvt_pk_f32_fp8(r1, false);
      floatx2 h1 = __builtin_amdgcn_cvt_pk_f32_fp8(r1, true);
      acc.x = fmaf(l1.x, c1, acc.x); acc.y = fmaf(l1.y, c1, acc.y);
      acc.z = fmaf(h1.x, c1, acc.z); acc.w = fmaf(h1.y, c1, acc.w);
      floatx2 l2 = __builtin_amdgcn_cvt_pk_f32_fp8(r2, false);
      floatx2 h2 = __builtin_amdgcn_cvt_pk_f32_fp8(r2, true);
      acc.x = fmaf(l2.x, c2, acc.x); acc.y = fmaf(l2.y, c2, acc.y);
      acc.z = fmaf(h2.x, c2, acc.z); acc.w = fmaf(h2.y, c2, acc.w);
      floatx2 l3 = __builtin_amdgcn_cvt_pk_f32_fp8(r3, false);
      floatx2 h3 = __builtin_amdgcn_cvt_pk_f32_fp8(r3, true);
      acc.x = fmaf(l3.x, c3, acc.x); acc.y = fmaf(l3.y, c3, acc.y);
      acc.z = fmaf(h3.x, c3, acc.z); acc.w = fmaf(h3.y, c3, acc.w);
    }
  }
  short4 pk;
  pk.x = (short)f2b(acc.x); pk.y = (short)f2b(acc.y);
  pk.z = (short)f2b(acc.z); pk.w = (short)f2b(acc.w);
  *(short4*)&accs[(w << 2) + sub][sl << 2] = pk;
  __syncthreads();

  // ---- MFMA: A[m=sl][k] from LDS; D col=lane&15, row=sub*4+reg ----
  bf16x8 a0 = *(const bf16x8*)&accs[sl][sub << 3];
  bf16x8 a1 = *(const bf16x8*)&accs[sl][32 + (sub << 3)];
  f32x4 c4 = {0.f, 0.f, 0.f, 0.f};
  c4 = __builtin_amdgcn_mfma_f32_16x16x32_bf16(a0, bf0, c4, 0, 0, 0);
  c4 = __builtin_amdgcn_mfma_f32_16x16x32_bf16(a1, bf1, c4, 0, 0, 0);

  float v[4];
#pragma unroll
  for (int r = 0; r < 4; r++) v[r] = c4[r] + bias_n;
#pragma unroll
  for (int r = 0; r < 4; r++) {
    float p = sub_sum16(v[r] * v[r]);
    if (sl == 0) ssq[(sub << 2) + r][w] = p;
  }
  __syncthreads();
#pragma unroll
  for (int r = 0; r < 4; r++) {
    int ml = (sub << 2) + r;  // local node (= D row)
    float4 s4 = *(const float4*)ssq[ml];
    float ss = s4.x + s4.y + s4.z + s4.w;
    float nrm = fmaxf(sqrtf(ss), 1e-12f);
    float h = v[r] / nrm;
    int gr = nb0 + ml;
    if (gr < NN) {
      int gn = permp[gr];
      long idx = (long)gn * 64 + ncol;
      if (MODE == 0) {
        out8[idx] = f2fp8(h);
      } else if (MODE == 2) {
        out8[(long)set * NE + idx] = f2fp8(h);
      } else if (MODE == 1) {
        float own = __builtin_amdgcn_cvt_f32_fp8((unsigned int)tbl[idx], 0);
        float b0 = (gn < NU) ? basef[idx] : base2f[(long)(gn - NU) * 64 + ncol];
        float rr = b0 + own + 0.5f * h;
        res16[idx] = f2b(rr);
        out8[idx] = f2fp8(rr);
      } else {  // MODE 3
        float own = __builtin_amdgcn_cvt_f32_fp8((unsigned int)tbl[idx], 0);
        float rr = b2f(base16[idx]) + own + 0.5f * h;
        (res16 + (long)set * NE)[idx] = f2b(rr);
      }
    }
  }
}

// ---------- fused attention + BPR loss (bf16 tables) ----------
__device__ inline void item_iw4(const unsigned short* __restrict__ G,
                                const unsigned short* __restrict__ B0,
                                const unsigned short* __restrict__ B1,
                                const unsigned short* __restrict__ B2,
                                long o, float4& iw0, float4& iw1, float4& iw2) {
  float4 g = ld4b(G + o);
  float4 t0 = ld4b(B0 + o);
  float4 t1 = ld4b(B1 + o);
  float4 t2 = ld4b(B2 + o);
  float g00 = sub_sum16(dot4(t0, t0)), g01 = sub_sum16(dot4(t0, t1));
  float g02 = sub_sum16(dot4(t0, t2)), g11 = sub_sum16(dot4(t1, t1));
  float g12 = sub_sum16(dot4(t1, t2)), g22 = sub_sum16(dot4(t2, t2));
  const float S = 0.125f;
  float gm[3][3] = {{g00, g01, g02}, {g01, g11, g12}, {g02, g12, g22}};
  float4* out[3] = {&iw0, &iw1, &iw2};
#pragma unroll
  for (int j = 0; j < 3; j++) {
    float a0 = gm[j][0] * S, a1 = gm[j][1] * S, a2 = gm[j][2] * S;
    float m = fmaxf(a0, fmaxf(a1, a2));
    float e0 = expf(a0 - m), e1 = expf(a1 - m), e2 = expf(a2 - m);
    float inv = 1.f / (e0 + e1 + e2);
    float w0 = e0 * inv, w1 = e1 * inv, w2 = e2 * inv;
    float4 r;
    r.x = fmaf(0.55f, w0 * t0.x + w1 * t1.x + w2 * t2.x, g.x);
    r.y = fmaf(0.55f, w0 * t0.y + w1 * t1.y + w2 * t2.y, g.y);
    r.z = fmaf(0.55f, w0 * t0.z + w1 * t1.z + w2 * t2.z, g.z);
    r.w = fmaf(0.55f, w0 * t0.w + w1 * t1.w + w2 * t2.w, g.w);
    *out[j] = r;
  }
}

__global__ void __launch_bounds__(256) k_loss(
    const unsigned short* __restrict__ G, const unsigned short* __restrict__ B0,
    const unsigned short* __restrict__ B1, const unsigned short* __restrict__ B2,
    const int* __restrict__ batch, float* __restrict__ acc) {
  int tid = blockIdx.x * blockDim.x + threadIdx.x;
  int lane = tid & 63;
  int sub = lane >> 4, sl = lane & 15;
  int task = (tid >> 6) * 4 + sub;  // task = k*3 + i
  if (task >= BATCH * 3) return;
  int i = task % 3;
  const int* bd = batch + (long)task * 3;
  int u = bd[0], p = bd[1], q = bd[2];

  float4 uf;
  {
    long o = (long)u * 64 + sl * 4;
    float4 g = ld4b(G + o);
    float4 t0 = ld4b(B0 + o);
    float4 t1 = ld4b(B1 + o);
    float4 t2 = ld4b(B2 + o);
    float4 ti = (i == 0) ? t0 : ((i == 1) ? t1 : t2);
    float a0 = sub_sum16(dot4(ti, t0)) * 0.125f;
    float a1 = sub_sum16(dot4(ti, t1)) * 0.125f;
    float a2 = sub_sum16(dot4(ti, t2)) * 0.125f;
    float m = fmaxf(a0, fmaxf(a1, a2));
    float e0 = expf(a0 - m), e1 = expf(a1 - m), e2 = expf(a2 - m);
    float inv = 1.f / (e0 + e1 + e2);
    float w0 = e0 * inv, w1 = e1 * inv, w2 = e2 * inv;
    uf.x = fmaf(2.35f, g.x, 0.242f * (w0 * t0.x + w1 * t1.x + w2 * t2.x));
    uf.y = fmaf(2.35f, g.y, 0.242f * (w0 * t0.y + w1 * t1.y + w2 * t2.y));
    uf.z = fmaf(2.35f, g.z, 0.242f * (w0 * t0.z + w1 * t1.z + w2 * t2.z));
    uf.w = fmaf(2.35f, g.w, 0.242f * (w0 * t0.w + w1 * t1.w + w2 * t2.w));
  }

  float4 p0, p1, p2, q0, q1, q2;
  item_iw4(G, B0, B1, B2, ((long)(NU + p)) * 64 + sl * 4, p0, p1, p2);
  item_iw4(G, B0, B1, B2, ((long)(NU + q)) * 64 + sl * 4, q0, q1, q2);

  float sp0 = sub_sum16(dot4(uf, p0)), sq0 = sub_sum16(dot4(uf, q0));
  float sp1 = sub_sum16(dot4(uf, p1)), sq1 = sub_sum16(dot4(uf, q1));
  float sp2 = sub_sum16(dot4(uf, p2)), sq2 = sub_sum16(dot4(uf, q2));

  if (sl == 0) {
    float loc = 0.f;
    float xs[3] = {sp0 - sq0, sp1 - sq1, sp2 - sq2};
#pragma unroll
    for (int j = 0; j < 3; j++) {
      float x = xs[j];
      loc += fminf(x, 0.f) - log1pf(expf(-fabsf(x)));
    }
    atomicAdd(acc, loc);
  }
}

// ---------- Frobenius sum-of-squares ----------
__global__ void k_sumsq(const float* __restrict__ x, long n, float* __restrict__ acc) {
  long stride = (long)gridDim.x * blockDim.x;
  float v = 0.f;
  for (long i = (long)blockIdx.x * blockDim.x + threadIdx.x; i < n; i += stride) {
    float t = x[i];
    v = fmaf(t, t, v);
  }
  v = wave_sum(v);
  if ((threadIdx.x & 63) == 0) atomicAdd(acc, v);
}

__global__ void k_final(const float* __restrict__ acc, float* __restrict__ out) {
  out[0] = -acc[0] * (1.0f / (float)BATCH) +
           0.001f * ((sqrtf(acc[1]) + sqrtf(acc[2])) / (float)NI);
}

// ---------- launch ----------
extern "C" void kernel_launch(void* const* d_in, const int* in_sizes, int n_in,
                              void* d_out, int out_size, void* d_ws, size_t ws_size,
                              hipStream_t stream) {
  const float* ue = (const float*)d_in[0];   // (60001, 64)
  const float* ie = (const float*)d_in[1];   // (40001, 64)
  const float* gW = (const float*)d_in[2];   // (2, 64, 64)
  const float* gb = (const float*)d_in[3];   // (2, 64)
  const float* bW = (const float*)d_in[4];   // (3, 2, 64, 64)
  const float* bb = (const float*)d_in[5];   // (3, 2, 64)
  const int* eg = (const int*)d_in[6];       // (2, 1e6)
  const int* eb = (const int*)d_in[7];       // (3, 2, 5e5)
  const int* batch = (const int*)d_in[8];    // (4096, 3, 3)
  float* out = (float*)d_out;

  const long NE = (long)NN * 64;
  unsigned short* G16 = (unsigned short*)d_ws;   // NE bf16
  unsigned short* B16 = G16 + NE;                // 3*NE bf16
  float* DINV = (float*)(B16 + 3 * NE);          // 4*NN
  float* ACC = DINV + 4 * NN;                    // 8
  int* CNT = (int*)(ACC + 8);                    // 4*NN
  int* OFFS = CNT + 4 * NN;                      // 4*NN
  int* CURS = OFFS + 4 * NN;                     // 4*NN
  int* PART = CURS + 4 * NN;                     // 4*256
  int* HIST = PART + 1024;                       // 4*64
  int* BCUR = HIST + 256;                        // 4*64
  int* PERM = BCUR + 256;                        // 4*NN
  int2* EDGES = (int2*)(PERM + 4 * NN);          // EG + 3*EB
  unsigned char* TB8 = (unsigned char*)(EDGES + EG + 3 * (long)EB);  // NE
  unsigned char* AGG8 = TB8 + NE;                                    // 3*NE

  hipMemsetAsync(ACC, 0, 8 * sizeof(float), stream);
  hipMemsetAsync(CNT, 0, 4 * NN * sizeof(int), stream);
  hipMemsetAsync(HIST, 0, 256 * sizeof(int), stream);

  const long n4 = (long)NN * 16;
  const int CP_B = (int)((n4 + 255) / 256);
  const int GB = (NN + 15) / 16;

  dim3 ge((EG + 255) / 256, 4);
  dim3 gn((NN + 255) / 256, 4);
  dim3 gs(196, 4);

  // ---- all 4 CSRs + degree-sorted perms (feature-independent) ----
  k_deg<<<ge, 256, 0, stream>>>(eg, eb, CNT);
  k_scanA<<<gs, 256, 0, stream>>>(CNT, OFFS, PART);
  k_scanB<<<4, 256, 0, stream>>>(PART);
  k_scanC<<<gn, 256, 0, stream>>>(OFFS, PART, CURS, CNT, DINV);
  k_hist<<<gn, 256, 0, stream>>>(CNT, HIST);
  k_scan64<<<1, 64, 0, stream>>>(HIST, BCUR);
  k_perm<<<gn, 256, 0, stream>>>(CNT, BCUR, PERM);
  k_bucket<<<ge, 256, 0, stream>>>(eg, eb, DINV, CURS, EDGES);

  // fp8 concat embedding table
  k_tofp8_concat<<<CP_B, 256, 0, stream>>>((const float4*)ue, (const float4*)ie,
                                           (unsigned int*)TB8);

  // ---- global encoder ----
  k_gcn<0><<<dim3(GB, 1), 256, 0, stream>>>(TB8, EDGES, OFFS, CNT, PERM, gW, gb,
                                            nullptr, nullptr, nullptr, nullptr, AGG8);
  k_gcn<1><<<dim3(GB, 1), 256, 0, stream>>>(AGG8, EDGES, OFFS, CNT, PERM, gW + 4096,
                                            gb + 64, ue, ie, nullptr, G16, TB8);

  // ---- behavior encoders (batched over 3 sets) ----
  k_gcn<2><<<dim3(GB, 3), 256, 0, stream>>>(TB8, EDGES, OFFS, CNT, PERM, bW, bb,
                                            nullptr, nullptr, nullptr, nullptr, AGG8);
  k_gcn<3><<<dim3(GB, 3), 256, 0, stream>>>(AGG8, EDGES, OFFS, CNT, PERM, bW, bb,
                                            nullptr, nullptr, G16, B16, nullptr);

  // ---- fused attention + BPR loss ----
  k_loss<<<(BATCH * 3) / 16, 256, 0, stream>>>(G16, B16, B16 + NE, B16 + 2 * NE,
                                               batch, ACC);

  // ---- regularization norms ----
  k_sumsq<<<512, 256, 0, stream>>>(ue, (long)NU * 64, ACC + 1);
  k_sumsq<<<512, 256, 0, stream>>>(ie, (long)NI * 64, ACC + 2);

  k_final<<<1, 1, 0, stream>>>(ACC, out);
}

// Round 8
// 685.198 us; speedup vs baseline: 2.1469x; 2.1469x over previous
//
#include <hip/hip_runtime.h>
#include <math.h>

#define NU 60001
#define NI 40001
#define NN 100002   // NU + NI
#define EG 1000000
#define EB 500000
#define BATCH 4096

typedef float floatx2 __attribute__((ext_vector_type(2)));
typedef short bf16x8 __attribute__((ext_vector_type(8)));
typedef float f32x4 __attribute__((ext_vector_type(4)));

// ---------- helpers ----------
__device__ inline float wave_sum(float v) {
#pragma unroll
  for (int off = 32; off > 0; off >>= 1) v += __shfl_down(v, off);
  return __shfl(v, 0);
}

__device__ inline float sub_sum16(float v) {  // reduce within 16-lane subgroup
#pragma unroll
  for (int off = 8; off > 0; off >>= 1) v += __shfl_xor(v, off);
  return v;
}

__device__ inline float dot4(float4 a, float4 b) {
  return fmaf(a.x, b.x, fmaf(a.y, b.y, fmaf(a.z, b.z, a.w * b.w)));
}

__device__ inline unsigned short f2b(float f) {  // fp32 -> bf16 RNE
  unsigned u = __float_as_uint(f);
  return (unsigned short)((u + 0x7fffu + ((u >> 16) & 1u)) >> 16);
}
__device__ inline float b2f(unsigned short h) {
  return __uint_as_float((unsigned)h << 16);
}
__device__ inline float4 ld4b(const unsigned short* p) {
  ushort4 u = *(const ushort4*)p;
  return make_float4(b2f(u.x), b2f(u.y), b2f(u.z), b2f(u.w));
}

// fp8 e4m3 (OCP) hardware converts
__device__ inline unsigned char f2fp8(float f) {
  return (unsigned char)(__builtin_amdgcn_cvt_pk_fp8_f32(f, f, 0, false) & 0xff);
}
__device__ inline unsigned int pack4_fp8(float4 v) {
  int pk = __builtin_amdgcn_cvt_pk_fp8_f32(v.x, v.y, 0, false);
  pk = __builtin_amdgcn_cvt_pk_fp8_f32(v.z, v.w, pk, true);
  return (unsigned int)pk;
}

// ---------- fp8 concat table ----------
__global__ void k_tofp8_concat(const float4* __restrict__ ue, const float4* __restrict__ ie,
                               unsigned int* __restrict__ out) {
  long i = (long)blockIdx.x * blockDim.x + threadIdx.x;  // over NN*16 float4s
  if (i >= (long)NN * 16) return;
  float4 v = (i < (long)NU * 16) ? ue[i] : ie[i - (long)NU * 16];
  out[i] = pack4_fp8(v);
}

// ---------- CSR build, batched over 4 sets (0=global, 1..3=behavior) ----------
__global__ void k_deg(const int* __restrict__ eg, const int* __restrict__ eb,
                      int* __restrict__ cnt4) {
  int set = blockIdx.y;
  int E = set ? EB : EG;
  int e = blockIdx.x * blockDim.x + threadIdx.x;
  if (e >= E) return;
  const int* dst = set ? (eb + (long)(set - 1) * 2 * EB + EB) : (eg + EG);
  atomicAdd(cnt4 + set * NN + dst[e], 1);
}

__global__ void k_scanA(const int* __restrict__ cnt, int* __restrict__ offs,
                        int* __restrict__ part) {
  __shared__ int sd[256];
  int t = threadIdx.x, set = blockIdx.y;
  int base = set * NN;
  int i0 = blockIdx.x * 512 + 2 * t, i1 = i0 + 1;
  int a = (i0 < NN) ? cnt[base + i0] : 0;
  int b = (i1 < NN) ? cnt[base + i1] : 0;
  sd[t] = a + b;
  __syncthreads();
  for (int off = 1; off < 256; off <<= 1) {
    int v = (t >= off) ? sd[t - off] : 0;
    __syncthreads();
    sd[t] += v;
    __syncthreads();
  }
  int excl = (t > 0) ? sd[t - 1] : 0;
  if (i0 < NN) offs[base + i0] = excl;
  if (i1 < NN) offs[base + i1] = excl + a;
  if (t == 255) part[set * 256 + blockIdx.x] = sd[255];
}

__global__ void k_scanB(int* __restrict__ part) {
  __shared__ int sd[256];
  int t = threadIdx.x, set = blockIdx.x;
  sd[t] = (t < 196) ? part[set * 256 + t] : 0;
  __syncthreads();
  for (int off = 1; off < 256; off <<= 1) {
    int v = (t >= off) ? sd[t - off] : 0;
    __syncthreads();
    sd[t] += v;
    __syncthreads();
  }
  part[set * 256 + t] = (t > 0) ? sd[t - 1] : 0;
}

__global__ void k_scanC(int* __restrict__ offs, const int* __restrict__ part,
                        int* __restrict__ curs, const int* __restrict__ cnt,
                        float* __restrict__ dinv) {
  int i = blockIdx.x * blockDim.x + threadIdx.x;
  int set = blockIdx.y;
  if (i < NN) {
    int gi = set * NN + i;
    int v = offs[gi] + part[set * 256 + (i >> 9)];
    offs[gi] = v;
    curs[gi] = v;
    int c = cnt[gi];
    dinv[gi] = (c > 0) ? rsqrtf((float)c) : 0.f;
  }
}

// edge payload: x = src byte-offset into fp8 table (src*64), y = coef bits
__global__ void k_bucket(const int* __restrict__ eg, const int* __restrict__ eb,
                         const float* __restrict__ dinv, int* __restrict__ curs,
                         int2* __restrict__ edges) {
  int set = blockIdx.y;
  int E = set ? EB : EG;
  int e = blockIdx.x * blockDim.x + threadIdx.x;
  if (e >= E) return;
  const int* sp = set ? (eb + (long)(set - 1) * 2 * EB) : eg;
  int s = sp[e], d = sp[E + e];
  int pos = atomicAdd(curs + set * NN + d, 1);
  long ebase = set ? (EG + (long)(set - 1) * EB) : 0;
  edges[ebase + pos] =
      make_int2(s << 6, __float_as_int(dinv[set * NN + s] * dinv[set * NN + d]));
}

// ---------- fused GCN layer: gather -> MFMA matvec -> bias -> l2norm -> out ----------
// 16 consecutive nodes per block (coalesced epilogue I/O).
// MODE 0: global l1  (tb=TB8,  out8=AGG8)
// MODE 1: global l2  (tb=AGG8, base=ue/ie f32, res16=G16, out8=TB8 shadow)
// MODE 2: behavior l1 (tb=TB8, out8=AGG8+set*NE), set = blockIdx.y
// MODE 3: behavior l2 (tb=AGG8+set*NE, base16=G16, res16=B16+set*NE)
template <int MODE>
__global__ void __launch_bounds__(256) k_gcn(
    const unsigned char* __restrict__ tb, const int2* __restrict__ edges,
    const int* __restrict__ offs, const int* __restrict__ cnt,
    const float* __restrict__ Wb, const float* __restrict__ biasb,
    const float* __restrict__ basef, const float* __restrict__ base2f,
    const unsigned short* __restrict__ base16,
    unsigned short* __restrict__ res16, unsigned char* __restrict__ out8) {
  __shared__ __align__(16) short accs[16][72];
  __shared__ float ssq[16][4];
  const long NE = (long)NN * 64;

  int t = threadIdx.x;
  int w = t >> 6, lane = t & 63;
  int sub = lane >> 4, sl = lane & 15;
  int set = blockIdx.y;

  const float *W, *bias;
  if (MODE <= 1) { W = Wb; bias = biasb; }
  else {
    W = Wb + (long)set * 8192 + (MODE == 3 ? 4096 : 0);
    bias = biasb + set * 128 + (MODE == 3 ? 64 : 0);
  }
  int cs = (MODE >= 2) ? (1 + set) : 0;
  const unsigned char* tbl = (MODE == 3) ? tb + (long)set * NE : tb;
  const int2* edg = (MODE >= 2) ? edges + EG + (long)set * EB : edges;
  const int* offp = offs + cs * NN;
  const int* cntp = cnt + cs * NN;

  // ---- B-frags: W columns in registers, bf16 ----
  int ncol = (w << 4) + sl;
  bf16x8 bf0, bf1;
#pragma unroll
  for (int j = 0; j < 8; j++) {
    bf0[j] = (short)f2b(W[(sub * 8 + j) * 64 + ncol]);
    bf1[j] = (short)f2b(W[(32 + sub * 8 + j) * 64 + ncol]);
  }
  float bias_n = bias[ncol];

  // ---- gather: node per subgroup ----
  int nb0 = blockIdx.x * 16;
  int node = nb0 + (w << 2) + sub;
  float4 acc = make_float4(0.f, 0.f, 0.f, 0.f);
  int st = 0, deg = 0;
  if (node < NN) { st = offp[node]; deg = cntp[node]; }
  int mx = deg;
  mx = max(mx, __shfl_xor(mx, 16));
  mx = max(mx, __shfl_xor(mx, 32));
  int lbase = lane & 48;  // sub*16
  for (int ch = 0; ch < mx; ch += 16) {
    int rem = deg - ch;
    int2 e = (sl < rem) ? edg[st + ch + sl] : make_int2(0, 0);
#pragma unroll
    for (int i = 0; i < 16; i += 4) {
      int j0 = lbase + i;
      int o0 = __shfl(e.x, j0),     c0i = __shfl(e.y, j0);
      int o1 = __shfl(e.x, j0 + 1), c1i = __shfl(e.y, j0 + 1);
      int o2 = __shfl(e.x, j0 + 2), c2i = __shfl(e.y, j0 + 2);
      int o3 = __shfl(e.x, j0 + 3), c3i = __shfl(e.y, j0 + 3);
      unsigned r0 = *(const unsigned*)(tbl + o0 + (sl << 2));
      unsigned r1 = *(const unsigned*)(tbl + o1 + (sl << 2));
      unsigned r2 = *(const unsigned*)(tbl + o2 + (sl << 2));
      unsigned r3 = *(const unsigned*)(tbl + o3 + (sl << 2));
      float c0 = __int_as_float(c0i), c1 = __int_as_float(c1i);
      float c2 = __int_as_float(c2i), c3 = __int_as_float(c3i);
      floatx2 l0 = __builtin_amdgcn_cvt_pk_f32_fp8(r0, false);
      floatx2 h0 = __builtin_amdgcn_cvt_pk_f32_fp8(r0, true);
      acc.x = fmaf(l0.x, c0, acc.x); acc.y = fmaf(l0.y, c0, acc.y);
      acc.z = fmaf(h0.x, c0, acc.z); acc.w = fmaf(h0.y, c0, acc.w);
      floatx2 l1 = __builtin_amdgcn_cvt_pk_f32_fp8(r1, false);
      floatx2 h1 = __builtin_amdgcn_cvt_pk_f32_fp8(r1, true);
      acc.x = fmaf(l1.x, c1, acc.x); acc.y = fmaf(l1.y, c1, acc.y);
      acc.z = fmaf(h1.x, c1, acc.z); acc.w = fmaf(h1.y, c1, acc.w);
      floatx2 l2 = __builtin_amdgcn_cvt_pk_f32_fp8(r2, false);
      floatx2 h2 = __builtin_amdgcn_cvt_pk_f32_fp8(r2, true);
      acc.x = fmaf(l2.x, c2, acc.x); acc.y = fmaf(l2.y, c2, acc.y);
      acc.z = fmaf(h2.x, c2, acc.z); acc.w = fmaf(h2.y, c2, acc.w);
      floatx2 l3 = __builtin_amdgcn_cvt_pk_f32_fp8(r3, false);
      floatx2 h3 = __builtin_amdgcn_cvt_pk_f32_fp8(r3, true);
      acc.x = fmaf(l3.x, c3, acc.x); acc.y = fmaf(l3.y, c3, acc.y);
      acc.z = fmaf(h3.x, c3, acc.z); acc.w = fmaf(h3.y, c3, acc.w);
    }
  }
  short4 pk;
  pk.x = (short)f2b(acc.x); pk.y = (short)f2b(acc.y);
  pk.z = (short)f2b(acc.z); pk.w = (short)f2b(acc.w);
  *(short4*)&accs[(w << 2) + sub][sl << 2] = pk;
  __syncthreads();

  // ---- MFMA: A[m=sl][k] from LDS; D col=lane&15, row=sub*4+reg ----
  bf16x8 a0 = *(const bf16x8*)&accs[sl][sub << 3];
  bf16x8 a1 = *(const bf16x8*)&accs[sl][32 + (sub << 3)];
  f32x4 c4 = {0.f, 0.f, 0.f, 0.f};
  c4 = __builtin_amdgcn_mfma_f32_16x16x32_bf16(a0, bf0, c4, 0, 0, 0);
  c4 = __builtin_amdgcn_mfma_f32_16x16x32_bf16(a1, bf1, c4, 0, 0, 0);

  float v[4];
#pragma unroll
  for (int r = 0; r < 4; r++) v[r] = c4[r] + bias_n;
#pragma unroll
  for (int r = 0; r < 4; r++) {
    float p = sub_sum16(v[r] * v[r]);
    if (sl == 0) ssq[(sub << 2) + r][w] = p;
  }
  __syncthreads();
#pragma unroll
  for (int r = 0; r < 4; r++) {
    int ml = (sub << 2) + r;  // local node (= D row)
    float4 s4 = *(const float4*)ssq[ml];
    float ss = s4.x + s4.y + s4.z + s4.w;
    float nrm = fmaxf(sqrtf(ss), 1e-12f);
    float h = v[r] / nrm;
    int gn = nb0 + ml;
    if (gn < NN) {
      long idx = (long)gn * 64 + ncol;
      if (MODE == 0) {
        out8[idx] = f2fp8(h);
      } else if (MODE == 2) {
        out8[(long)set * NE + idx] = f2fp8(h);
      } else if (MODE == 1) {
        float own = __builtin_amdgcn_cvt_f32_fp8((unsigned int)tbl[idx], 0);
        float b0 = (gn < NU) ? basef[idx] : base2f[(long)(gn - NU) * 64 + ncol];
        float rr = b0 + own + 0.5f * h;
        res16[idx] = f2b(rr);
        out8[idx] = f2fp8(rr);
      } else {  // MODE 3
        float own = __builtin_amdgcn_cvt_f32_fp8((unsigned int)tbl[idx], 0);
        float rr = b2f(base16[idx]) + own + 0.5f * h;
        (res16 + (long)set * NE)[idx] = f2b(rr);
      }
    }
  }
}

// ---------- fused attention + BPR loss (bf16 tables) ----------
__device__ inline void item_iw4(const unsigned short* __restrict__ G,
                                const unsigned short* __restrict__ B0,
                                const unsigned short* __restrict__ B1,
                                const unsigned short* __restrict__ B2,
                                long o, float4& iw0, float4& iw1, float4& iw2) {
  float4 g = ld4b(G + o);
  float4 t0 = ld4b(B0 + o);
  float4 t1 = ld4b(B1 + o);
  float4 t2 = ld4b(B2 + o);
  float g00 = sub_sum16(dot4(t0, t0)), g01 = sub_sum16(dot4(t0, t1));
  float g02 = sub_sum16(dot4(t0, t2)), g11 = sub_sum16(dot4(t1, t1));
  float g12 = sub_sum16(dot4(t1, t2)), g22 = sub_sum16(dot4(t2, t2));
  const float S = 0.125f;
  float gm[3][3] = {{g00, g01, g02}, {g01, g11, g12}, {g02, g12, g22}};
  float4* out[3] = {&iw0, &iw1, &iw2};
#pragma unroll
  for (int j = 0; j < 3; j++) {
    float a0 = gm[j][0] * S, a1 = gm[j][1] * S, a2 = gm[j][2] * S;
    float m = fmaxf(a0, fmaxf(a1, a2));
    float e0 = expf(a0 - m), e1 = expf(a1 - m), e2 = expf(a2 - m);
    float inv = 1.f / (e0 + e1 + e2);
    float w0 = e0 * inv, w1 = e1 * inv, w2 = e2 * inv;
    float4 r;
    r.x = fmaf(0.55f, w0 * t0.x + w1 * t1.x + w2 * t2.x, g.x);
    r.y = fmaf(0.55f, w0 * t0.y + w1 * t1.y + w2 * t2.y, g.y);
    r.z = fmaf(0.55f, w0 * t0.z + w1 * t1.z + w2 * t2.z, g.z);
    r.w = fmaf(0.55f, w0 * t0.w + w1 * t1.w + w2 * t2.w, g.w);
    *out[j] = r;
  }
}

__global__ void __launch_bounds__(256) k_loss(
    const unsigned short* __restrict__ G, const unsigned short* __restrict__ B0,
    const unsigned short* __restrict__ B1, const unsigned short* __restrict__ B2,
    const int* __restrict__ batch, float* __restrict__ acc) {
  int tid = blockIdx.x * blockDim.x + threadIdx.x;
  int lane = tid & 63;
  int sub = lane >> 4, sl = lane & 15;
  int task = (tid >> 6) * 4 + sub;  // task = k*3 + i
  if (task >= BATCH * 3) return;
  int i = task % 3;
  const int* bd = batch + (long)task * 3;
  int u = bd[0], p = bd[1], q = bd[2];

  float4 uf;
  {
    long o = (long)u * 64 + sl * 4;
    float4 g = ld4b(G + o);
    float4 t0 = ld4b(B0 + o);
    float4 t1 = ld4b(B1 + o);
    float4 t2 = ld4b(B2 + o);
    float4 ti = (i == 0) ? t0 : ((i == 1) ? t1 : t2);
    float a0 = sub_sum16(dot4(ti, t0)) * 0.125f;
    float a1 = sub_sum16(dot4(ti, t1)) * 0.125f;
    float a2 = sub_sum16(dot4(ti, t2)) * 0.125f;
    float m = fmaxf(a0, fmaxf(a1, a2));
    float e0 = expf(a0 - m), e1 = expf(a1 - m), e2 = expf(a2 - m);
    float inv = 1.f / (e0 + e1 + e2);
    float w0 = e0 * inv, w1 = e1 * inv, w2 = e2 * inv;
    uf.x = fmaf(2.35f, g.x, 0.242f * (w0 * t0.x + w1 * t1.x + w2 * t2.x));
    uf.y = fmaf(2.35f, g.y, 0.242f * (w0 * t0.y + w1 * t1.y + w2 * t2.y));
    uf.z = fmaf(2.35f, g.z, 0.242f * (w0 * t0.z + w1 * t1.z + w2 * t2.z));
    uf.w = fmaf(2.35f, g.w, 0.242f * (w0 * t0.w + w1 * t1.w + w2 * t2.w));
  }

  float4 p0, p1, p2, q0, q1, q2;
  item_iw4(G, B0, B1, B2, ((long)(NU + p)) * 64 + sl * 4, p0, p1, p2);
  item_iw4(G, B0, B1, B2, ((long)(NU + q)) * 64 + sl * 4, q0, q1, q2);

  float sp0 = sub_sum16(dot4(uf, p0)), sq0 = sub_sum16(dot4(uf, q0));
  float sp1 = sub_sum16(dot4(uf, p1)), sq1 = sub_sum16(dot4(uf, q1));
  float sp2 = sub_sum16(dot4(uf, p2)), sq2 = sub_sum16(dot4(uf, q2));

  if (sl == 0) {
    float loc = 0.f;
    float xs[3] = {sp0 - sq0, sp1 - sq1, sp2 - sq2};
#pragma unroll
    for (int j = 0; j < 3; j++) {
      float x = xs[j];
      loc += fminf(x, 0.f) - log1pf(expf(-fabsf(x)));
    }
    atomicAdd(acc, loc);
  }
}

// ---------- Frobenius sum-of-squares ----------
__global__ void k_sumsq(const float* __restrict__ x, long n, float* __restrict__ acc) {
  long stride = (long)gridDim.x * blockDim.x;
  float v = 0.f;
  for (long i = (long)blockIdx.x * blockDim.x + threadIdx.x; i < n; i += stride) {
    float t = x[i];
    v = fmaf(t, t, v);
  }
  v = wave_sum(v);
  if ((threadIdx.x & 63) == 0) atomicAdd(acc, v);
}

__global__ void k_final(const float* __restrict__ acc, float* __restrict__ out) {
  out[0] = -acc[0] * (1.0f / (float)BATCH) +
           0.001f * ((sqrtf(acc[1]) + sqrtf(acc[2])) / (float)NI);
}

// ---------- launch ----------
extern "C" void kernel_launch(void* const* d_in, const int* in_sizes, int n_in,
                              void* d_out, int out_size, void* d_ws, size_t ws_size,
                              hipStream_t stream) {
  const float* ue = (const float*)d_in[0];   // (60001, 64)
  const float* ie = (const float*)d_in[1];   // (40001, 64)
  const float* gW = (const float*)d_in[2];   // (2, 64, 64)
  const float* gb = (const float*)d_in[3];   // (2, 64)
  const float* bW = (const float*)d_in[4];   // (3, 2, 64, 64)
  const float* bb = (const float*)d_in[5];   // (3, 2, 64)
  const int* eg = (const int*)d_in[6];       // (2, 1e6)
  const int* eb = (const int*)d_in[7];       // (3, 2, 5e5)
  const int* batch = (const int*)d_in[8];    // (4096, 3, 3)
  float* out = (float*)d_out;

  const long NE = (long)NN * 64;
  unsigned short* G16 = (unsigned short*)d_ws;   // NE bf16
  unsigned short* B16 = G16 + NE;                // 3*NE bf16
  float* DINV = (float*)(B16 + 3 * NE);          // 4*NN
  float* ACC = DINV + 4 * NN;                    // 8
  int* CNT = (int*)(ACC + 8);                    // 4*NN
  int* OFFS = CNT + 4 * NN;                      // 4*NN
  int* CURS = OFFS + 4 * NN;                     // 4*NN
  int* PART = CURS + 4 * NN;                     // 4*256
  int2* EDGES = (int2*)(PART + 1024);            // EG + 3*EB
  unsigned char* TB8 = (unsigned char*)(EDGES + EG + 3 * (long)EB);  // NE
  unsigned char* AGG8 = TB8 + NE;                                    // 3*NE

  hipMemsetAsync(ACC, 0, 8 * sizeof(float), stream);
  hipMemsetAsync(CNT, 0, 4 * NN * sizeof(int), stream);

  const long n4 = (long)NN * 16;
  const int CP_B = (int)((n4 + 255) / 256);
  const int GB = (NN + 15) / 16;

  dim3 ge((EG + 255) / 256, 4);
  dim3 gn((NN + 255) / 256, 4);
  dim3 gs(196, 4);

  // ---- all 4 CSRs (feature-independent) ----
  k_deg<<<ge, 256, 0, stream>>>(eg, eb, CNT);
  k_scanA<<<gs, 256, 0, stream>>>(CNT, OFFS, PART);
  k_scanB<<<4, 256, 0, stream>>>(PART);
  k_scanC<<<gn, 256, 0, stream>>>(OFFS, PART, CURS, CNT, DINV);
  k_bucket<<<ge, 256, 0, stream>>>(eg, eb, DINV, CURS, EDGES);

  // fp8 concat embedding table
  k_tofp8_concat<<<CP_B, 256, 0, stream>>>((const float4*)ue, (const float4*)ie,
                                           (unsigned int*)TB8);

  // ---- global encoder ----
  k_gcn<0><<<dim3(GB, 1), 256, 0, stream>>>(TB8, EDGES, OFFS, CNT, gW, gb,
                                            nullptr, nullptr, nullptr, nullptr, AGG8);
  k_gcn<1><<<dim3(GB, 1), 256, 0, stream>>>(AGG8, EDGES, OFFS, CNT, gW + 4096, gb + 64,
                                            ue, ie, nullptr, G16, TB8);

  // ---- behavior encoders (batched over 3 sets) ----
  k_gcn<2><<<dim3(GB, 3), 256, 0, stream>>>(TB8, EDGES, OFFS, CNT, bW, bb,
                                            nullptr, nullptr, nullptr, nullptr, AGG8);
  k_gcn<3><<<dim3(GB, 3), 256, 0, stream>>>(AGG8, EDGES, OFFS, CNT, bW, bb,
                                            nullptr, nullptr, G16, B16, nullptr);

  // ---- fused attention + BPR loss ----
  k_loss<<<(BATCH * 3) / 16, 256, 0, stream>>>(G16, B16, B16 + NE, B16 + 2 * NE,
                                               batch, ACC);

  // ---- regularization norms ----
  k_sumsq<<<512, 256, 0, stream>>>(ue, (long)NU * 64, ACC + 1);
  k_sumsq<<<512, 256, 0, stream>>>(ie, (long)NI * 64, ACC + 2);

  k_final<<<1, 1, 0, stream>>>(ACC, out);
}